// Round 9
// baseline (263.616 us; speedup 1.0000x reference)
//
#include <hip/hip_runtime.h>

// Problem constants (fixed by setup_inputs):
//   x: [B=64, D=64, H=32, W=32] fp32   -> N = B*H*W = 65536 rows of D=64
//   codebook: [K=512, D=64] fp32
// Output layout (all fp32, concatenated flat in return order):
//   [0 .. 4194304)        quant_out [B,D,H,W]
//   [4194304]             loss
//   [4194305]             perplexity
//   [4194306 .. +65536)   encoding_indice [B, H*W] (as float)
//   [4259842 .. +32768)   index_program [B,K]
//   [4292610 .. +32768)   softmax_histogram [B,K]

#define OFF_LOSS 4194304
#define OFF_PERP 4194305
#define OFF_ENC  4194306
#define OFF_IP   4259842
#define OFF_SH   4292610

// Workspace layout (floats). Requires ws_size >= 561729*4 B = 2.25 MB.
//   cbT  [4][64][128]        chunk-major transposed codebook
//   ce2  [512]               ||e_k||^2
//   sh partials [1024][512]  per-block softmax-histogram partial
//   loss partials [1024*4]   per-wave loss partial
//   counters [65] (as int)   64 per-batch + 1 global, zeroed by vq_prep
#define WS_CBT   0
#define WS_CE2   32768
#define WS_SHP   33280
#define WS_LOSS  557568
#define WS_CNT   561664

// R16 changes:
//  - vq_main GEMM/epilogue: EXACT R14 (109 us steady; R15's full-LDS
//    d-outer regressed to 129 us -- 1 block/CU starved latency hiding).
//  - vq_reduce + vq_final FUSED into vq_main via last-block-done pattern
//    (threadfence + device atomics; counters zeroed by vq_prep each launch,
//    graph-replay safe). 4 kernels -> 2: kills ~2 launch gaps + 2 small
//    dispatch tails (~64 us of the 173 us end-to-end was non-main).
//  - Fused finalization replicates the old kernels' summation orders
//    exactly (j 0..15 chains, c0..c3 bb-stride-4 grouping, wave-tree ->
//    red[0..7] order via a/b halves) -> outputs bit-identical to R14.

typedef float f16v __attribute__((ext_vector_type(16)));

typedef __attribute__((address_space(1))) const void g_void;
typedef __attribute__((address_space(3))) void lds_void;
#define GLOAD_LDS(G, S) \
    __builtin_amdgcn_global_load_lds((g_void*)(G), (lds_void*)(S), 16, 0, 0)

__global__ __launch_bounds__(256) void vq_prep(const float* __restrict__ cb,
                                               float* __restrict__ ws)
{
    // zero the completion counters (every launch: graph replay safe)
    if (blockIdx.x == 0 && threadIdx.x < 65)
        ((int*)ws)[WS_CNT + threadIdx.x] = 0;

    const int t  = blockIdx.x * 256 + threadIdx.x;   // 0..8191
    const int kg = t >> 4;                           // code 0..511
    const int j  = t & 15;                           // float4 index along D
    const float4 v = ((const float4*)cb)[(kg << 4) + j];
    float pr = v.x * v.x + v.y * v.y + v.z * v.z + v.w * v.w;
    #pragma unroll
    for (int off = 1; off < 16; off <<= 1) pr += __shfl_xor(pr, off, 16);
    if (j == 0) ws[WS_CE2 + kg] = pr;
    // transposed, chunk-major: ws[WS_CBT + kc*8192 + d*128 + kl]
    const int kc = kg >> 7, kl = kg & 127;
    float* base = ws + WS_CBT + (kc << 13) + (j << 9) + kl;   // d = 4*j
    base[0]   = v.x;
    base[128] = v.y;
    base[256] = v.z;
    base[384] = v.w;
}

// ---- macro kit: all acc element indices are integer literals ----
#define FMA4(ACC, AV, K4) \
    ACC[(K4) + 0] = fmaf((AV), bq.x, ACC[(K4) + 0]); \
    ACC[(K4) + 1] = fmaf((AV), bq.y, ACC[(K4) + 1]); \
    ACC[(K4) + 2] = fmaf((AV), bq.z, ACC[(K4) + 2]); \
    ACC[(K4) + 3] = fmaf((AV), bq.w, ACC[(K4) + 3]);

// stage one 128-code chunk of cbT into csT via direct global->LDS DMA
#define STAGE_CST(KC) do { \
    GLOAD_LDS(&cbT4[((KC) << 11) + t],        &csT4[t]); \
    GLOAD_LDS(&cbT4[((KC) << 11) + 256 + t],  &csT4[256 + t]); \
    GLOAD_LDS(&cbT4[((KC) << 11) + 512 + t],  &csT4[512 + t]); \
    GLOAD_LDS(&cbT4[((KC) << 11) + 768 + t],  &csT4[768 + t]); \
    GLOAD_LDS(&cbT4[((KC) << 11) + 1024 + t], &csT4[1024 + t]); \
    GLOAD_LDS(&cbT4[((KC) << 11) + 1280 + t], &csT4[1280 + t]); \
    GLOAD_LDS(&cbT4[((KC) << 11) + 1536 + t], &csT4[1536 + t]); \
    GLOAD_LDS(&cbT4[((KC) << 11) + 1792 + t], &csT4[1792 + t]); \
} while (0)

// 64-d FMA sweep over the staged chunk. Per (row,k): d ascending within
// chunk, chunks ascending -- same fmaf chain as R12/R14.
#define GEMM_COMPUTE(KC) do { \
    _Pragma("unroll 2") \
    for (int db = 0; db < 16; ++db) { \
        const float* cbase = &csT[(db << 9) + (tc << 2)]; \
        _Pragma("unroll") \
        for (int j = 0; j < 4; ++j) { \
            const int d = (db << 2) + j; \
            const float4 a0 = *(const float4*)&xs[(d << 6) + (tr << 3)]; \
            const float4 a1 = *(const float4*)&xs[(d << 6) + (tr << 3) + 4]; \
            const float4 bq = *(const float4*)&cbase[j << 7]; \
            FMA4(acc0, a0.x, (KC) << 2) \
            FMA4(acc1, a0.y, (KC) << 2) \
            FMA4(acc2, a0.z, (KC) << 2) \
            FMA4(acc3, a0.w, (KC) << 2) \
            FMA4(acc4, a1.x, (KC) << 2) \
            FMA4(acc5, a1.y, (KC) << 2) \
            FMA4(acc6, a1.z, (KC) << 2) \
            FMA4(acc7, a1.w, (KC) << 2) \
        } \
    } \
} while (0)

#define EPI_C(C, ACC) { \
    const int k = (((C) >> 2) << 7) + (tc << 2) + ((C) & 3); \
    const float t1 = xxr + ce2[k]; \
    const float dist = t1 - 2.f * ACC[C]; \
    ACC[C] = dist; \
    if (dist < m) { m = dist; bk = k; } }

#define EXP_C(C, ACC) { \
    const float e = __expf(m - ACC[C]); \
    ACC[C] = e; z += e; }

#define ROW_EPI(I, ACC, INVZ) do { \
    const int row = (tr << 3) + (I); \
    const float xxr = sxx[row]; \
    float m = 1e30f; int bk = 0; \
    EPI_C(0, ACC)  EPI_C(1, ACC)  EPI_C(2, ACC)  EPI_C(3, ACC) \
    EPI_C(4, ACC)  EPI_C(5, ACC)  EPI_C(6, ACC)  EPI_C(7, ACC) \
    EPI_C(8, ACC)  EPI_C(9, ACC)  EPI_C(10, ACC) EPI_C(11, ACC) \
    EPI_C(12, ACC) EPI_C(13, ACC) EPI_C(14, ACC) EPI_C(15, ACC) \
    _Pragma("unroll") \
    for (int off = 1; off < 32; off <<= 1) { \
        const float mo = __shfl_xor(m, off, 32); \
        const int   ko = __shfl_xor(bk, off, 32); \
        if (mo < m || (mo == m && ko < bk)) { m = mo; bk = ko; } \
    } \
    float z = 0.f; \
    EXP_C(0, ACC)  EXP_C(1, ACC)  EXP_C(2, ACC)  EXP_C(3, ACC) \
    EXP_C(4, ACC)  EXP_C(5, ACC)  EXP_C(6, ACC)  EXP_C(7, ACC) \
    EXP_C(8, ACC)  EXP_C(9, ACC)  EXP_C(10, ACC) EXP_C(11, ACC) \
    EXP_C(12, ACC) EXP_C(13, ACC) EXP_C(14, ACC) EXP_C(15, ACC) \
    _Pragma("unroll") \
    for (int off = 1; off < 32; off <<= 1) z += __shfl_xor(z, off, 32); \
    INVZ = 1.f / z; \
    if (tc == 0) { \
        sidx[row] = bk; \
        enc[((size_t)b << 10) + row0 + row] = (float)bk; \
    } \
} while (0)

#define HIST_C(C) { \
    const int k = (((C) >> 2) << 7) + (tc << 2) + ((C) & 3); \
    float cs = 0.f; \
    cs += acc0[C] * invz0; cs += acc1[C] * invz1; \
    cs += acc2[C] * invz2; cs += acc3[C] * invz3; \
    cs += acc4[C] * invz4; cs += acc5[C] * invz5; \
    cs += acc6[C] * invz6; cs += acc7[C] * invz7; \
    atomicAdd(&shist[k], cs); }

__global__ __launch_bounds__(256, 1) void vq_main(
    const float* __restrict__ x, const float* __restrict__ cb,
    const float* __restrict__ wsc,   // cbT + ce2 (read-only region)
    float* __restrict__ wso,         // sh + loss partials + counters
    float* __restrict__ out)
{
    __shared__ float  xs[64 * 64];     // xs[d*64 + r], transposed x tile (64 rows)
    __shared__ float  csT[64 * 128];   // [d][k] for current 128-code chunk
    __shared__ float  ce2[512];        // ||e_k||^2 (fp32)
    __shared__ float  sxx[64];         // ||x_r||^2 (fp32) per row
    __shared__ int    sidx[64];        // argmin code per row
    __shared__ int    s_last;

    const int t    = threadIdx.x;
    const int blk  = blockIdx.x;        // 0..1023
    const int b    = blk >> 4;          // batch index
    const int row0 = (blk & 15) << 6;   // row offset within batch (H*W space)
    const int tr   = t >> 5;            // 0..7  (row group: rows tr*8..tr*8+7)
    const int tc   = t & 31;            // 0..31 (col group)

    const float4* cbT4 = (const float4*)(wsc + WS_CBT);
    float4* csT4 = (float4*)csT;

    // ---- stage x tile via global->LDS DMA (lane-linear: lds = base+lane*16) ----
    {
        const float4* xb4 = (const float4*)(x + ((size_t)b << 16) + row0);
        #pragma unroll
        for (int p = 0; p < 4; ++p) {
            const int fi = (p << 8) + t;      // 0..1023
            const int d  = fi >> 4;
            const int r4 = fi & 15;
            GLOAD_LDS(&xb4[(d << 8) + r4], &xs[(d << 6) + (r4 << 2)]);
        }
    }
    // ---- stage chunk 0 of codebook ----
    STAGE_CST(0);
    // ---- stage ce2 from ws (plain load/store, drained by the barrier) ----
    if (t < 128) ((float4*)ce2)[t] = ((const float4*)(wsc + WS_CE2))[t];

    __syncthreads();   // drains vmcnt(0): xs + csT chunk 0 + ce2 ready

    // ---- ||x_r||^2 fp32, sequential fmaf over d (bit-exact) ----
    if (t < 64) {
        float s = 0.f;
        for (int d = 0; d < 64; ++d) { const float v = xs[(d << 6) + t]; s = fmaf(v, v, s); }
        sxx[t] = s;
    }

    f16v acc0 = 0.f, acc1 = 0.f, acc2 = 0.f, acc3 = 0.f;
    f16v acc4 = 0.f, acc5 = 0.f, acc6 = 0.f, acc7 = 0.f;

    // ---- GEMM: 4 chunks of 128 codes (kc literal -> all acc indices literal) ----
    GEMM_COMPUTE(0);
    __syncthreads();   // all waves done reading csT chunk 0
    STAGE_CST(1);
    __syncthreads();   // vmcnt drained: chunk 1 ready (sxx also visible)
    GEMM_COMPUTE(1);
    __syncthreads();
    STAGE_CST(2);
    __syncthreads();
    GEMM_COMPUTE(2);
    __syncthreads();
    STAGE_CST(3);
    __syncthreads();
    GEMM_COMPUTE(3);

    // ---- epilogue: ref-exact fp32 dist; per-row argmin + softmax(-dist) ----
    float* enc = out + OFF_ENC;
    float invz0, invz1, invz2, invz3, invz4, invz5, invz6, invz7;
    ROW_EPI(0, acc0, invz0);
    ROW_EPI(1, acc1, invz1);
    ROW_EPI(2, acc2, invz2);
    ROW_EPI(3, acc3, invz3);
    ROW_EPI(4, acc4, invz4);
    ROW_EPI(5, acc5, invz5);
    ROW_EPI(6, acc6, invz6);
    ROW_EPI(7, acc7, invz7);

    __syncthreads();   // all csT reads done; sidx visible

    // ---- softmax histogram: block-reduce in LDS (alias csT), partial to ws ----
    float* shist = csT;
    shist[t] = 0.f; shist[t + 256] = 0.f;
    __syncthreads();
    HIST_C(0)  HIST_C(1)  HIST_C(2)  HIST_C(3)
    HIST_C(4)  HIST_C(5)  HIST_C(6)  HIST_C(7)
    HIST_C(8)  HIST_C(9)  HIST_C(10) HIST_C(11)
    HIST_C(12) HIST_C(13) HIST_C(14) HIST_C(15)
    __syncthreads();
    {
        float* wsh = wso + WS_SHP + ((size_t)blk << 9);
        wsh[t]       = shist[t];
        wsh[t + 256] = shist[t + 256];
    }

    // ---- quantized output + loss partial (from sidx), vectorized ----
    const int r4 = (t & 15) << 2;          // row quad 0..60
    const int dq = t >> 4;                 // 0..15
    const int c0 = sidx[r4], c1 = sidx[r4 + 1], c2 = sidx[r4 + 2], c3 = sidx[r4 + 3];
    float lsum = 0.f;
    #pragma unroll
    for (int p = 0; p < 4; ++p) {
        const int d = (p << 4) + dq;
        float4 q;
        q.x = cb[(c0 << 6) + d];
        q.y = cb[(c1 << 6) + d];
        q.z = cb[(c2 << 6) + d];
        q.w = cb[(c3 << 6) + d];
        const float4 xv = *(const float4*)&xs[(d << 6) + r4];
        const float d0 = q.x - xv.x, d1 = q.y - xv.y, d2 = q.z - xv.z, d3 = q.w - xv.w;
        lsum = fmaf(d0, d0, lsum); lsum = fmaf(d1, d1, lsum);
        lsum = fmaf(d2, d2, lsum); lsum = fmaf(d3, d3, lsum);
        *(float4*)&out[(((size_t)(b << 6) + d) << 10) + row0 + r4] = q;
    }
    #pragma unroll
    for (int off = 1; off < 64; off <<= 1) lsum += __shfl_xor(lsum, off, 64);
    if ((t & 63) == 0) wso[WS_LOSS + (blk << 2) + (t >> 6)] = lsum;

    // ================= fused reduce/final (last-block-done) =================
    int* cnts = (int*)wso;
    __threadfence();   // make this block's out/ws writes device-visible
    if (t == 0) s_last = (atomicAdd(&cnts[WS_CNT + b], 1) == 15);
    __syncthreads();
    if (!s_last) return;

    // ---- per-batch reduce (this block is the 16th finisher of batch b) ----
    // sh: sum 16 partials per column, j ascending (bit-identical to old
    // vq_reduce: per-column sequential chain)
    {
        const float* p = wso + WS_SHP + (((size_t)b << 4) << 9);   // b*16*512
        float s0 = 0.f, s1 = 0.f;
        #pragma unroll
        for (int j = 0; j < 16; ++j) {
            s0 += p[(j << 9) + t];
            s1 += p[(j << 9) + t + 256];
        }
        out[OFF_SH + (b << 9) + t]       = s0;
        out[OFF_SH + (b << 9) + t + 256] = s1;
    }
    // ip: integer histogram of enc[b][0..1023] (exact regardless of order)
    {
        int* hist = (int*)csT;
        hist[t] = 0; hist[t + 256] = 0;
        __syncthreads();
        const float* encb = out + OFF_ENC + ((size_t)b << 10);
        atomicAdd(&hist[(int)encb[t]], 1);
        atomicAdd(&hist[(int)encb[t + 256]], 1);
        atomicAdd(&hist[(int)encb[t + 512]], 1);
        atomicAdd(&hist[(int)encb[t + 768]], 1);
        __syncthreads();
        out[OFF_IP + (b << 9) + t]       = (float)hist[t];
        out[OFF_IP + (b << 9) + t + 256] = (float)hist[t + 256];
    }

    __threadfence();
    if (t == 0) s_last = (atomicAdd(&cnts[WS_CNT + 64], 1) == 63);
    __syncthreads();
    if (!s_last) return;

    // ---- global final (64th reducer): loss sum + perplexity ----
    // Replicates old vq_final exactly: 512 virtual threads = 256 threads x
    // {k=t (a-half), k=t+256 (b-half)}; per-k c0..c3 bb-stride-4 grouping;
    // 64-lane trees; red[0..7] summed in order (a0..a3 then b0..b3).
    {
        float ha, hb;
        {
            float c0 = 0.f, c1 = 0.f, c2 = 0.f, c3 = 0.f;
            #pragma unroll
            for (int bb = 0; bb < 64; bb += 4) {
                c0 += out[OFF_IP + ((bb + 0) << 9) + t];
                c1 += out[OFF_IP + ((bb + 1) << 9) + t];
                c2 += out[OFF_IP + ((bb + 2) << 9) + t];
                c3 += out[OFF_IP + ((bb + 3) << 9) + t];
            }
            const float c = (c0 + c1) + (c2 + c3);
            const float pav = c * (1.0f / 65536.f);
            ha = pav * logf(pav + 1e-10f);
        }
        {
            float c0 = 0.f, c1 = 0.f, c2 = 0.f, c3 = 0.f;
            #pragma unroll
            for (int bb = 0; bb < 64; bb += 4) {
                c0 += out[OFF_IP + ((bb + 0) << 9) + t + 256];
                c1 += out[OFF_IP + ((bb + 1) << 9) + t + 256];
                c2 += out[OFF_IP + ((bb + 2) << 9) + t + 256];
                c3 += out[OFF_IP + ((bb + 3) << 9) + t + 256];
            }
            const float c = (c0 + c1) + (c2 + c3);
            const float pav = c * (1.0f / 65536.f);
            hb = pav * logf(pav + 1e-10f);
        }
        float la = 0.f, lb = 0.f;
        #pragma unroll
        for (int j = 0; j < 8; ++j) {
            la += wso[WS_LOSS + (j << 9) + t];
            lb += wso[WS_LOSS + (j << 9) + t + 256];
        }
        #pragma unroll
        for (int off = 1; off < 64; off <<= 1) {
            ha += __shfl_xor(ha, off, 64);
            hb += __shfl_xor(hb, off, 64);
            la += __shfl_xor(la, off, 64);
            lb += __shfl_xor(lb, off, 64);
        }
        __shared__ float sra[4], srb[4], s2a[4], s2b[4];
        if ((t & 63) == 0) {
            const int w = t >> 6;
            sra[w] = ha; srb[w] = hb; s2a[w] = la; s2b[w] = lb;
        }
        __syncthreads();
        if (t == 0) {
            float H = 0.f, L = 0.f;
            H += sra[0]; H += sra[1]; H += sra[2]; H += sra[3];
            H += srb[0]; H += srb[1]; H += srb[2]; H += srb[3];
            L += s2a[0]; L += s2a[1]; L += s2a[2]; L += s2a[3];
            L += s2b[0]; L += s2b[1]; L += s2b[2]; L += s2b[3];
            out[OFF_PERP] = expf(-H);
            out[OFF_LOSS] = L * (1.25f / 4194304.f);
        }
    }
}

extern "C" void kernel_launch(void* const* d_in, const int* in_sizes, int n_in,
                              void* d_out, int out_size, void* d_ws, size_t ws_size,
                              hipStream_t stream)
{
    const float* x  = (const float*)d_in[0];
    const float* cb = (const float*)d_in[1];
    float* out = (float*)d_out;
    float* ws  = (float*)d_ws;
    (void)ws_size;   // requires >= 2.25 MB (561729 floats)

    vq_prep <<<32,   256, 0, stream>>>(cb, ws);
    vq_main <<<1024, 256, 0, stream>>>(x, cb, ws, ws, out);
}

// Round 10
// 216.060 us; speedup vs baseline: 1.2201x; 1.2201x over previous
//
#include <hip/hip_runtime.h>

// Problem constants (fixed by setup_inputs):
//   x: [B=64, D=64, H=32, W=32] fp32   -> N = B*H*W = 65536 rows of D=64
//   codebook: [K=512, D=64] fp32
// Output layout (all fp32, concatenated flat in return order):
//   [0 .. 4194304)        quant_out [B,D,H,W]
//   [4194304]             loss
//   [4194305]             perplexity
//   [4194306 .. +65536)   encoding_indice [B, H*W] (as float)
//   [4259842 .. +32768)   index_program [B,K]
//   [4292610 .. +32768)   softmax_histogram [B,K]

#define OFF_LOSS 4194304
#define OFF_PERP 4194305
#define OFF_ENC  4194306
#define OFF_IP   4259842
#define OFF_SH   4292610

// Workspace layout (floats). Requires ws_size >= 561729*4 B = 2.25 MB.
//   cbT  [4][64][128]        chunk-major transposed codebook
//   ce2  [512]               ||e_k||^2
//   sh partials [1024][512]  per-block softmax-histogram partial
//   loss partials [1024*4]   per-wave loss partial
//   counter [1] (int)        tail completion counter, zeroed by vq_prep
#define WS_CBT   0
#define WS_CE2   32768
#define WS_SHP   33280
#define WS_LOSS  557568
#define WS_CNT   561664

// R17 (revert R16's fused-main disaster; two safe deltas vs R14):
//  - R16 lesson [measured]: device-scope release fence in every main block
//    = per-wave wait for its own quant stores to reach the coherence point
//    (8 non-coherent L2s) -> +107 us. Never fence the big kernel.
//    Launch-boundary cost measured at ~5.5 us (R14 vs R16 overhead delta).
//  - (a) vq_main: R14 GEMM, but chunks split into d-halves (32x128=16KB),
//    double-buffered cs0/cs1. Next seg's global_load_lds issue BEFORE the
//    current seg's FMA sweep -> the pre-barrier vmcnt(0) drain is free.
//    Per-(row,k) chain: d still ascends 0..63 within its chunk (d-split,
//    not k-split) -> bit-exact vs R14.
//  - (b) vq_reduce+vq_final fused into vq_tail (64 blocks, last-block-done;
//    fences cover only ~4KB of stores per block). Bodies verbatim. 4->3
//    dispatches.

typedef float f16v __attribute__((ext_vector_type(16)));

typedef __attribute__((address_space(1))) const void g_void;
typedef __attribute__((address_space(3))) void lds_void;
#define GLOAD_LDS(G, S) \
    __builtin_amdgcn_global_load_lds((g_void*)(G), (lds_void*)(S), 16, 0, 0)

__global__ __launch_bounds__(256) void vq_prep(const float* __restrict__ cb,
                                               float* __restrict__ ws)
{
    if (blockIdx.x == 0 && threadIdx.x == 0)
        ((int*)ws)[WS_CNT] = 0;   // every launch: graph-replay safe

    const int t  = blockIdx.x * 256 + threadIdx.x;   // 0..8191
    const int kg = t >> 4;                           // code 0..511
    const int j  = t & 15;                           // float4 index along D
    const float4 v = ((const float4*)cb)[(kg << 4) + j];
    float pr = v.x * v.x + v.y * v.y + v.z * v.z + v.w * v.w;
    #pragma unroll
    for (int off = 1; off < 16; off <<= 1) pr += __shfl_xor(pr, off, 16);
    if (j == 0) ws[WS_CE2 + kg] = pr;
    // transposed, chunk-major: ws[WS_CBT + kc*8192 + d*128 + kl]
    const int kc = kg >> 7, kl = kg & 127;
    float* base = ws + WS_CBT + (kc << 13) + (j << 9) + kl;   // d = 4*j
    base[0]   = v.x;
    base[128] = v.y;
    base[256] = v.z;
    base[384] = v.w;
}

// ---- macro kit: all acc element indices are integer literals ----
#define FMA4(ACC, AV, K4) \
    ACC[(K4) + 0] = fmaf((AV), bq.x, ACC[(K4) + 0]); \
    ACC[(K4) + 1] = fmaf((AV), bq.y, ACC[(K4) + 1]); \
    ACC[(K4) + 2] = fmaf((AV), bq.z, ACC[(K4) + 2]); \
    ACC[(K4) + 3] = fmaf((AV), bq.w, ACC[(K4) + 3]);

// stage one seg (= chunk kc, d-half h; seg index S = kc*2+h) into a buffer.
// cbT is contiguous per seg: float4 range [S*1024, S*1024+1024).
#define STAGE_SEG(S, BUF4) do { \
    GLOAD_LDS(&cbT4[((S) << 10) + t],       &BUF4[t]); \
    GLOAD_LDS(&cbT4[((S) << 10) + 256 + t], &BUF4[256 + t]); \
    GLOAD_LDS(&cbT4[((S) << 10) + 512 + t], &BUF4[512 + t]); \
    GLOAD_LDS(&cbT4[((S) << 10) + 768 + t], &BUF4[768 + t]); \
} while (0)

// 32-d FMA sweep over one seg. KC,H literals. Per (row,k): d ascending
// (H=0: d 0..31, H=1: d 32..63) -> same per-acc chain as R14.
#define COMPUTE_SEG(KC, H, BUF) do { \
    _Pragma("unroll 2") \
    for (int db = 0; db < 8; ++db) { \
        const float* cbase = &BUF[(db << 9) + (tc << 2)]; \
        _Pragma("unroll") \
        for (int j = 0; j < 4; ++j) { \
            const int d = ((H) << 5) + (db << 2) + j; \
            const float4 a0 = *(const float4*)&xs[(d << 6) + (tr << 3)]; \
            const float4 a1 = *(const float4*)&xs[(d << 6) + (tr << 3) + 4]; \
            const float4 bq = *(const float4*)&cbase[j << 7]; \
            FMA4(acc0, a0.x, (KC) << 2) \
            FMA4(acc1, a0.y, (KC) << 2) \
            FMA4(acc2, a0.z, (KC) << 2) \
            FMA4(acc3, a0.w, (KC) << 2) \
            FMA4(acc4, a1.x, (KC) << 2) \
            FMA4(acc5, a1.y, (KC) << 2) \
            FMA4(acc6, a1.z, (KC) << 2) \
            FMA4(acc7, a1.w, (KC) << 2) \
        } \
    } \
} while (0)

#define EPI_C(C, ACC) { \
    const int k = (((C) >> 2) << 7) + (tc << 2) + ((C) & 3); \
    const float t1 = xxr + ce2[k]; \
    const float dist = t1 - 2.f * ACC[C]; \
    ACC[C] = dist; \
    if (dist < m) { m = dist; bk = k; } }

#define EXP_C(C, ACC) { \
    const float e = __expf(m - ACC[C]); \
    ACC[C] = e; z += e; }

#define ROW_EPI(I, ACC, INVZ) do { \
    const int row = (tr << 3) + (I); \
    const float xxr = sxx[row]; \
    float m = 1e30f; int bk = 0; \
    EPI_C(0, ACC)  EPI_C(1, ACC)  EPI_C(2, ACC)  EPI_C(3, ACC) \
    EPI_C(4, ACC)  EPI_C(5, ACC)  EPI_C(6, ACC)  EPI_C(7, ACC) \
    EPI_C(8, ACC)  EPI_C(9, ACC)  EPI_C(10, ACC) EPI_C(11, ACC) \
    EPI_C(12, ACC) EPI_C(13, ACC) EPI_C(14, ACC) EPI_C(15, ACC) \
    _Pragma("unroll") \
    for (int off = 1; off < 32; off <<= 1) { \
        const float mo = __shfl_xor(m, off, 32); \
        const int   ko = __shfl_xor(bk, off, 32); \
        if (mo < m || (mo == m && ko < bk)) { m = mo; bk = ko; } \
    } \
    float z = 0.f; \
    EXP_C(0, ACC)  EXP_C(1, ACC)  EXP_C(2, ACC)  EXP_C(3, ACC) \
    EXP_C(4, ACC)  EXP_C(5, ACC)  EXP_C(6, ACC)  EXP_C(7, ACC) \
    EXP_C(8, ACC)  EXP_C(9, ACC)  EXP_C(10, ACC) EXP_C(11, ACC) \
    EXP_C(12, ACC) EXP_C(13, ACC) EXP_C(14, ACC) EXP_C(15, ACC) \
    _Pragma("unroll") \
    for (int off = 1; off < 32; off <<= 1) z += __shfl_xor(z, off, 32); \
    INVZ = 1.f / z; \
    if (tc == 0) { \
        sidx[row] = bk; \
        enc[((size_t)b << 10) + row0 + row] = (float)bk; \
    } \
} while (0)

#define HIST_C(C) { \
    const int k = (((C) >> 2) << 7) + (tc << 2) + ((C) & 3); \
    float cs = 0.f; \
    cs += acc0[C] * invz0; cs += acc1[C] * invz1; \
    cs += acc2[C] * invz2; cs += acc3[C] * invz3; \
    cs += acc4[C] * invz4; cs += acc5[C] * invz5; \
    cs += acc6[C] * invz6; cs += acc7[C] * invz7; \
    atomicAdd(&shist[k], cs); }

__global__ __launch_bounds__(256, 1) void vq_main(
    const float* __restrict__ x, const float* __restrict__ cb,
    const float* __restrict__ wsc,   // cbT + ce2 (read-only region)
    float* __restrict__ wso,         // sh + loss partials (write-only region)
    float* __restrict__ out)
{
    __shared__ float  xs[64 * 64];     // xs[d*64 + r], transposed x tile
    __shared__ float  cs0[32 * 128];   // seg buffer A (16 KB)
    __shared__ float  cs1[32 * 128];   // seg buffer B (16 KB)
    __shared__ float  ce2[512];        // ||e_k||^2 (fp32)
    __shared__ float  sxx[64];         // ||x_r||^2 (fp32) per row
    __shared__ int    sidx[64];        // argmin code per row

    const int t    = threadIdx.x;
    const int blk  = blockIdx.x;        // 0..1023
    const int b    = blk >> 4;          // batch index
    const int row0 = (blk & 15) << 6;   // row offset within batch (H*W space)
    const int tr   = t >> 5;            // 0..7  (row group: rows tr*8..tr*8+7)
    const int tc   = t & 31;            // 0..31 (col group)

    const float4* cbT4 = (const float4*)(wsc + WS_CBT);
    float4* cs0_4 = (float4*)cs0;
    float4* cs1_4 = (float4*)cs1;

    // ---- stage x tile + seg0 via global->LDS DMA (lane-linear) ----
    {
        const float4* xb4 = (const float4*)(x + ((size_t)b << 16) + row0);
        #pragma unroll
        for (int p = 0; p < 4; ++p) {
            const int fi = (p << 8) + t;      // 0..1023
            const int d  = fi >> 4;
            const int r4 = fi & 15;
            GLOAD_LDS(&xb4[(d << 8) + r4], &xs[(d << 6) + (r4 << 2)]);
        }
    }
    STAGE_SEG(0, cs0_4);
    if (t < 128) ((float4*)ce2)[t] = ((const float4*)(wsc + WS_CE2))[t];

    __syncthreads();   // drains vmcnt(0): xs + seg0 + ce2 ready

    // ---- ||x_r||^2 fp32, sequential fmaf over d (bit-exact) ----
    if (t < 64) {
        float s = 0.f;
        for (int d = 0; d < 64; ++d) { const float v = xs[(d << 6) + t]; s = fmaf(v, v, s); }
        sxx[t] = s;
    }

    f16v acc0 = 0.f, acc1 = 0.f, acc2 = 0.f, acc3 = 0.f;
    f16v acc4 = 0.f, acc5 = 0.f, acc6 = 0.f, acc7 = 0.f;

    // ---- GEMM: 8 segs, double-buffered. Stage of seg s+1 issues BEFORE
    //      the FMA sweep of seg s -> loads land under compute; the
    //      compiler's pre-barrier vmcnt(0) drain is then ~free. ----
    STAGE_SEG(1, cs1_4);  COMPUTE_SEG(0, 0, cs0);  __syncthreads();
    STAGE_SEG(2, cs0_4);  COMPUTE_SEG(0, 1, cs1);  __syncthreads();
    STAGE_SEG(3, cs1_4);  COMPUTE_SEG(1, 0, cs0);  __syncthreads();
    STAGE_SEG(4, cs0_4);  COMPUTE_SEG(1, 1, cs1);  __syncthreads();
    STAGE_SEG(5, cs1_4);  COMPUTE_SEG(2, 0, cs0);  __syncthreads();
    STAGE_SEG(6, cs0_4);  COMPUTE_SEG(2, 1, cs1);  __syncthreads();
    STAGE_SEG(7, cs1_4);  COMPUTE_SEG(3, 0, cs0);  __syncthreads();
    COMPUTE_SEG(3, 1, cs1);

    // ---- epilogue: ref-exact fp32 dist; per-row argmin + softmax(-dist) ----
    float* enc = out + OFF_ENC;
    float invz0, invz1, invz2, invz3, invz4, invz5, invz6, invz7;
    ROW_EPI(0, acc0, invz0);
    ROW_EPI(1, acc1, invz1);
    ROW_EPI(2, acc2, invz2);
    ROW_EPI(3, acc3, invz3);
    ROW_EPI(4, acc4, invz4);
    ROW_EPI(5, acc5, invz5);
    ROW_EPI(6, acc6, invz6);
    ROW_EPI(7, acc7, invz7);

    __syncthreads();   // all cs reads done; sidx visible

    // ---- softmax histogram: block-reduce in LDS (alias cs0), partial to ws ----
    float* shist = cs0;
    shist[t] = 0.f; shist[t + 256] = 0.f;
    __syncthreads();
    HIST_C(0)  HIST_C(1)  HIST_C(2)  HIST_C(3)
    HIST_C(4)  HIST_C(5)  HIST_C(6)  HIST_C(7)
    HIST_C(8)  HIST_C(9)  HIST_C(10) HIST_C(11)
    HIST_C(12) HIST_C(13) HIST_C(14) HIST_C(15)
    __syncthreads();
    {
        float* wsh = wso + WS_SHP + ((size_t)blk << 9);
        wsh[t]       = shist[t];
        wsh[t + 256] = shist[t + 256];
    }

    // ---- quantized output + loss partial (from sidx), vectorized ----
    const int r4 = (t & 15) << 2;          // row quad 0..60
    const int dq = t >> 4;                 // 0..15
    const int c0 = sidx[r4], c1 = sidx[r4 + 1], c2 = sidx[r4 + 2], c3 = sidx[r4 + 3];
    float lsum = 0.f;
    #pragma unroll
    for (int p = 0; p < 4; ++p) {
        const int d = (p << 4) + dq;
        float4 q;
        q.x = cb[(c0 << 6) + d];
        q.y = cb[(c1 << 6) + d];
        q.z = cb[(c2 << 6) + d];
        q.w = cb[(c3 << 6) + d];
        const float4 xv = *(const float4*)&xs[(d << 6) + r4];
        const float d0 = q.x - xv.x, d1 = q.y - xv.y, d2 = q.z - xv.z, d3 = q.w - xv.w;
        lsum = fmaf(d0, d0, lsum); lsum = fmaf(d1, d1, lsum);
        lsum = fmaf(d2, d2, lsum); lsum = fmaf(d3, d3, lsum);
        *(float4*)&out[(((size_t)(b << 6) + d) << 10) + row0 + r4] = q;
    }
    #pragma unroll
    for (int off = 1; off < 64; off <<= 1) lsum += __shfl_xor(lsum, off, 64);
    if ((t & 63) == 0) wso[WS_LOSS + (blk << 2) + (t >> 6)] = lsum;
}

// fused vq_reduce + vq_final: 64 blocks; last-block-done (cheap fences:
// each block has only ~4 KB of outstanding stores). Bodies verbatim from
// the R14 kernels -> bit-identical outputs.
__global__ __launch_bounds__(512) void vq_tail(float* __restrict__ ws,
                                               float* __restrict__ out)
{
    __shared__ int hist[512];
    __shared__ int s_last;
    const int b = blockIdx.x, t = threadIdx.x;
    const float* p = ws + WS_SHP + ((size_t)b << 13) + t;   // b*16*512
    float s = 0.f;
    #pragma unroll
    for (int j = 0; j < 16; ++j) s += p[j << 9];
    out[OFF_SH + (b << 9) + t] = s;
    hist[t] = 0;
    __syncthreads();
    const float* enc = out + OFF_ENC + ((size_t)b << 10);
    const int ca  = (int)enc[t];
    const int cbn = (int)enc[t + 512];
    atomicAdd(&hist[ca], 1);
    atomicAdd(&hist[cbn], 1);
    __syncthreads();
    out[OFF_IP + (b << 9) + t] = (float)hist[t];

    __threadfence();   // release this block's ip/sh writes
    if (t == 0) s_last = (atomicAdd(&((int*)ws)[WS_CNT], 1) == 63);
    __syncthreads();
    if (!s_last) return;
    __threadfence();   // acquire other blocks' ip writes

    // ---- vq_final body (verbatim) ----
    __shared__ float red[8], red2[8];
    const float* ip = out + OFF_IP;
    float c0 = 0.f, c1 = 0.f, c2 = 0.f, c3 = 0.f;
    #pragma unroll
    for (int bb = 0; bb < 64; bb += 4) {
        c0 += ip[((bb + 0) << 9) + t];
        c1 += ip[((bb + 1) << 9) + t];
        c2 += ip[((bb + 2) << 9) + t];
        c3 += ip[((bb + 3) << 9) + t];
    }
    const float c = (c0 + c1) + (c2 + c3);
    const float pav = c * (1.0f / 65536.f);
    float h = pav * logf(pav + 1e-10f);
    const float* wl = ws + WS_LOSS;
    float ls = 0.f;
    #pragma unroll
    for (int j = 0; j < 8; ++j) ls += wl[(j << 9) + t];
    #pragma unroll
    for (int off = 1; off < 64; off <<= 1) {
        h  += __shfl_xor(h, off, 64);
        ls += __shfl_xor(ls, off, 64);
    }
    if ((t & 63) == 0) { red[t >> 6] = h; red2[t >> 6] = ls; }
    __syncthreads();
    if (t == 0) {
        float H = 0.f, L = 0.f;
        #pragma unroll
        for (int w = 0; w < 8; ++w) { H += red[w]; L += red2[w]; }
        out[OFF_PERP] = expf(-H);
        out[OFF_LOSS] = L * (1.25f / 4194304.f);
    }
}

extern "C" void kernel_launch(void* const* d_in, const int* in_sizes, int n_in,
                              void* d_out, int out_size, void* d_ws, size_t ws_size,
                              hipStream_t stream)
{
    const float* x  = (const float*)d_in[0];
    const float* cb = (const float*)d_in[1];
    float* out = (float*)d_out;
    float* ws  = (float*)d_ws;
    (void)ws_size;   // requires >= 2.25 MB (561729 floats)

    vq_prep <<<32,   256, 0, stream>>>(cb, ws);
    vq_main <<<1024, 256, 0, stream>>>(x, cb, ws, ws, out);
    vq_tail <<<64,   512, 0, stream>>>(ws, out);
}

// Round 11
// 192.375 us; speedup vs baseline: 1.3703x; 1.1231x over previous
//
#include <hip/hip_runtime.h>

// Problem constants (fixed by setup_inputs):
//   x: [B=64, D=64, H=32, W=32] fp32   -> N = B*H*W = 65536 rows of D=64
//   codebook: [K=512, D=64] fp32
// Output layout (all fp32, concatenated flat in return order):
//   [0 .. 4194304)        quant_out [B,D,H,W]
//   [4194304]             loss
//   [4194305]             perplexity
//   [4194306 .. +65536)   encoding_indice [B, H*W] (as float)
//   [4259842 .. +32768)   index_program [B,K]
//   [4292610 .. +32768)   softmax_histogram [B,K]

#define OFF_LOSS 4194304
#define OFF_PERP 4194305
#define OFF_ENC  4194306
#define OFF_IP   4259842
#define OFF_SH   4292610

// Workspace layout (floats). Requires ws_size >= 1090049*4 B = 4.36 MB.
//   cbT  [4][64][128]        chunk-major transposed codebook
//   ce2  [512]               ||e_k||^2
//   sh partials [2048][512]  per-block softmax-histogram partial
//   loss partials [2048*4]   per-wave loss partial
//   counter [1] (int)        tail completion counter, zeroed by vq_prep
#define WS_CBT   0
#define WS_CE2   32768
#define WS_SHP   33280
#define WS_LOSS  1081856
#define WS_CNT   1090048

// R18 (occupancy rebuild; math bit-identical to R12 per (row,k)):
//  - R17 lesson [measured]: R14 sat EXACTLY on the 256-reg/wave boundary
//    (128 arch + 128 acc); +4 arch VGPRs halved occupancy (19->11%) and
//    cost +36 us. The 8x16 tile can never exceed 2 waves/SIMD.
//  - Fix: 4x16 tile (acc=64; R12's GEMM/epilogue chains verbatim, passed
//    at 7.6e-6) + R14's global_load_lds staging (no pv regs, no ds_writes).
//    Total regs ~115 -> 3 waves/SIMD with ~55-reg margin (no cliff).
//    LDS 42.7 KB -> 3 blocks/CU = 12 waves/CU (1.5x R14's residency).
//  - Tail fused (R17's vq_tail, 32 partials/batch). 3 dispatches.

typedef float f16v __attribute__((ext_vector_type(16)));

typedef __attribute__((address_space(1))) const void g_void;
typedef __attribute__((address_space(3))) void lds_void;
#define GLOAD_LDS(G, S) \
    __builtin_amdgcn_global_load_lds((g_void*)(G), (lds_void*)(S), 16, 0, 0)

__global__ __launch_bounds__(256) void vq_prep(const float* __restrict__ cb,
                                               float* __restrict__ ws)
{
    if (blockIdx.x == 0 && threadIdx.x == 0)
        ((int*)ws)[WS_CNT] = 0;   // every launch: graph-replay safe

    const int t  = blockIdx.x * 256 + threadIdx.x;   // 0..8191
    const int kg = t >> 4;                           // code 0..511
    const int j  = t & 15;                           // float4 index along D
    const float4 v = ((const float4*)cb)[(kg << 4) + j];
    float pr = v.x * v.x + v.y * v.y + v.z * v.z + v.w * v.w;
    #pragma unroll
    for (int off = 1; off < 16; off <<= 1) pr += __shfl_xor(pr, off, 16);
    if (j == 0) ws[WS_CE2 + kg] = pr;
    // transposed, chunk-major: ws[WS_CBT + kc*8192 + d*128 + kl]
    const int kc = kg >> 7, kl = kg & 127;
    float* base = ws + WS_CBT + (kc << 13) + (j << 9) + kl;   // d = 4*j
    base[0]   = v.x;
    base[128] = v.y;
    base[256] = v.z;
    base[384] = v.w;
}

// ---- macro kit: all acc element indices are integer literals ----
#define FMA4(ACC, AV, K4) \
    ACC[(K4) + 0] = fmaf((AV), bq.x, ACC[(K4) + 0]); \
    ACC[(K4) + 1] = fmaf((AV), bq.y, ACC[(K4) + 1]); \
    ACC[(K4) + 2] = fmaf((AV), bq.z, ACC[(K4) + 2]); \
    ACC[(K4) + 3] = fmaf((AV), bq.w, ACC[(K4) + 3]);

// stage one 128-code chunk of cbT into csT via direct global->LDS DMA
#define STAGE_CST(KC) do { \
    GLOAD_LDS(&cbT4[((KC) << 11) + t],        &csT4[t]); \
    GLOAD_LDS(&cbT4[((KC) << 11) + 256 + t],  &csT4[256 + t]); \
    GLOAD_LDS(&cbT4[((KC) << 11) + 512 + t],  &csT4[512 + t]); \
    GLOAD_LDS(&cbT4[((KC) << 11) + 768 + t],  &csT4[768 + t]); \
    GLOAD_LDS(&cbT4[((KC) << 11) + 1024 + t], &csT4[1024 + t]); \
    GLOAD_LDS(&cbT4[((KC) << 11) + 1280 + t], &csT4[1280 + t]); \
    GLOAD_LDS(&cbT4[((KC) << 11) + 1536 + t], &csT4[1536 + t]); \
    GLOAD_LDS(&cbT4[((KC) << 11) + 1792 + t], &csT4[1792 + t]); \
} while (0)

// 64-d FMA sweep over the staged chunk. Per (row,k): d ascending within
// chunk, chunks ascending -- R12's exact fmaf chain.
#define GEMM_COMPUTE(KC) do { \
    _Pragma("unroll 2") \
    for (int db = 0; db < 16; ++db) { \
        const float* cbase = &csT[(db << 9) + (tc << 2)]; \
        _Pragma("unroll") \
        for (int j = 0; j < 4; ++j) { \
            const int d = (db << 2) + j; \
            const float4 a0 = *(const float4*)&xs[(d << 5) + (tr << 2)]; \
            const float4 bq = *(const float4*)&cbase[j << 7]; \
            FMA4(acc0, a0.x, (KC) << 2) \
            FMA4(acc1, a0.y, (KC) << 2) \
            FMA4(acc2, a0.z, (KC) << 2) \
            FMA4(acc3, a0.w, (KC) << 2) \
        } \
    } \
} while (0)

#define EPI_C(C, ACC) { \
    const int k = (((C) >> 2) << 7) + (tc << 2) + ((C) & 3); \
    const float t1 = xxr + ce2[k]; \
    const float dist = t1 - 2.f * ACC[C]; \
    ACC[C] = dist; \
    if (dist < m) { m = dist; bk = k; } }

#define EXP_C(C, ACC) { \
    const float e = __expf(m - ACC[C]); \
    ACC[C] = e; z += e; }

#define ROW_EPI(I, ACC, INVZ) do { \
    const int row = (tr << 2) + (I); \
    const float xxr = sxx[row]; \
    float m = 1e30f; int bk = 0; \
    EPI_C(0, ACC)  EPI_C(1, ACC)  EPI_C(2, ACC)  EPI_C(3, ACC) \
    EPI_C(4, ACC)  EPI_C(5, ACC)  EPI_C(6, ACC)  EPI_C(7, ACC) \
    EPI_C(8, ACC)  EPI_C(9, ACC)  EPI_C(10, ACC) EPI_C(11, ACC) \
    EPI_C(12, ACC) EPI_C(13, ACC) EPI_C(14, ACC) EPI_C(15, ACC) \
    _Pragma("unroll") \
    for (int off = 1; off < 32; off <<= 1) { \
        const float mo = __shfl_xor(m, off, 32); \
        const int   ko = __shfl_xor(bk, off, 32); \
        if (mo < m || (mo == m && ko < bk)) { m = mo; bk = ko; } \
    } \
    float z = 0.f; \
    EXP_C(0, ACC)  EXP_C(1, ACC)  EXP_C(2, ACC)  EXP_C(3, ACC) \
    EXP_C(4, ACC)  EXP_C(5, ACC)  EXP_C(6, ACC)  EXP_C(7, ACC) \
    EXP_C(8, ACC)  EXP_C(9, ACC)  EXP_C(10, ACC) EXP_C(11, ACC) \
    EXP_C(12, ACC) EXP_C(13, ACC) EXP_C(14, ACC) EXP_C(15, ACC) \
    _Pragma("unroll") \
    for (int off = 1; off < 32; off <<= 1) z += __shfl_xor(z, off, 32); \
    INVZ = 1.f / z; \
    if (tc == 0) { \
        sidx[row] = bk; \
        enc[((size_t)b << 10) + row0 + row] = (float)bk; \
    } \
} while (0)

#define HIST_C(C) { \
    const int k = (((C) >> 2) << 7) + (tc << 2) + ((C) & 3); \
    float cs = 0.f; \
    cs += acc0[C] * invz0; cs += acc1[C] * invz1; \
    cs += acc2[C] * invz2; cs += acc3[C] * invz3; \
    atomicAdd(&shist[k], cs); }

__global__ __launch_bounds__(256, 1) void vq_main(
    const float* __restrict__ x, const float* __restrict__ cb,
    const float* __restrict__ wsc,   // cbT + ce2 (read-only region)
    float* __restrict__ wso,         // sh + loss partials (write-only region)
    float* __restrict__ out)
{
    __shared__ float  xs[64 * 32];     // xs[d*32 + r], transposed x tile (32 rows)
    __shared__ float  csT[64 * 128];   // [d][k] for current 128-code chunk
    __shared__ float  ce2[512];        // ||e_k||^2 (fp32)
    __shared__ float  sxx[32];         // ||x_r||^2 (fp32) per row
    __shared__ int    sidx[32];        // argmin code per row

    const int t    = threadIdx.x;
    const int blk  = blockIdx.x;        // 0..2047
    const int b    = blk >> 5;          // batch index
    const int row0 = (blk & 31) << 5;   // row offset within batch (H*W space)
    const int tr   = t >> 5;            // 0..7  (row group: rows tr*4..tr*4+3)
    const int tc   = t & 31;            // 0..31 (col group)

    const float4* cbT4 = (const float4*)(wsc + WS_CBT);
    float4* csT4 = (float4*)csT;

    // ---- stage x tile via global->LDS DMA (lane-linear: lds = base+fi*16) ----
    {
        const float4* xb4 = (const float4*)(x + ((size_t)b << 16) + row0);
        #pragma unroll
        for (int p = 0; p < 2; ++p) {
            const int fi = (p << 8) + t;      // 0..511
            const int d  = fi >> 3;
            const int r4 = fi & 7;
            GLOAD_LDS(&xb4[(d << 8) + r4], &xs[(d << 5) + (r4 << 2)]);
        }
    }
    // ---- stage chunk 0 of codebook ----
    STAGE_CST(0);
    // ---- stage ce2 from ws (plain load/store, drained by the barrier) ----
    if (t < 128) ((float4*)ce2)[t] = ((const float4*)(wsc + WS_CE2))[t];

    __syncthreads();   // drains vmcnt(0): xs + csT chunk 0 + ce2 ready

    // ---- ||x_r||^2 fp32, sequential fmaf over d (bit-exact) ----
    if (t < 32) {
        float s = 0.f;
        for (int d = 0; d < 64; ++d) { const float v = xs[(d << 5) + t]; s = fmaf(v, v, s); }
        sxx[t] = s;
    }

    f16v acc0 = 0.f, acc1 = 0.f, acc2 = 0.f, acc3 = 0.f;

    // ---- GEMM: 4 chunks of 128 codes (kc literal -> all acc indices literal) ----
    GEMM_COMPUTE(0);
    __syncthreads();   // all waves done reading csT chunk 0
    STAGE_CST(1);
    __syncthreads();   // vmcnt drained: chunk 1 ready (sxx also visible)
    GEMM_COMPUTE(1);
    __syncthreads();
    STAGE_CST(2);
    __syncthreads();
    GEMM_COMPUTE(2);
    __syncthreads();
    STAGE_CST(3);
    __syncthreads();
    GEMM_COMPUTE(3);

    // ---- epilogue: ref-exact fp32 dist; per-row argmin + softmax(-dist) ----
    float* enc = out + OFF_ENC;
    float invz0, invz1, invz2, invz3;
    ROW_EPI(0, acc0, invz0);
    ROW_EPI(1, acc1, invz1);
    ROW_EPI(2, acc2, invz2);
    ROW_EPI(3, acc3, invz3);

    __syncthreads();   // all csT reads done; sidx visible

    // ---- softmax histogram: block-reduce in LDS (alias csT), partial to ws ----
    float* shist = csT;
    shist[t] = 0.f; shist[t + 256] = 0.f;
    __syncthreads();
    HIST_C(0)  HIST_C(1)  HIST_C(2)  HIST_C(3)
    HIST_C(4)  HIST_C(5)  HIST_C(6)  HIST_C(7)
    HIST_C(8)  HIST_C(9)  HIST_C(10) HIST_C(11)
    HIST_C(12) HIST_C(13) HIST_C(14) HIST_C(15)
    __syncthreads();
    {
        float* wsh = wso + WS_SHP + ((size_t)blk << 9);
        wsh[t]       = shist[t];
        wsh[t + 256] = shist[t + 256];
    }

    // ---- quantized output + loss partial (from sidx), vectorized ----
    const int r4 = (t & 7) << 2;           // row quad 0..28
    const int dq = t >> 3;                 // 0..31
    const int c0 = sidx[r4], c1 = sidx[r4 + 1], c2 = sidx[r4 + 2], c3 = sidx[r4 + 3];
    float lsum = 0.f;
    #pragma unroll
    for (int p = 0; p < 2; ++p) {
        const int d = (p << 5) + dq;
        float4 q;
        q.x = cb[(c0 << 6) + d];
        q.y = cb[(c1 << 6) + d];
        q.z = cb[(c2 << 6) + d];
        q.w = cb[(c3 << 6) + d];
        const float4 xv = *(const float4*)&xs[(d << 5) + r4];
        const float d0 = q.x - xv.x, d1 = q.y - xv.y, d2 = q.z - xv.z, d3 = q.w - xv.w;
        lsum = fmaf(d0, d0, lsum); lsum = fmaf(d1, d1, lsum);
        lsum = fmaf(d2, d2, lsum); lsum = fmaf(d3, d3, lsum);
        *(float4*)&out[(((size_t)(b << 6) + d) << 10) + row0 + r4] = q;
    }
    #pragma unroll
    for (int off = 1; off < 64; off <<= 1) lsum += __shfl_xor(lsum, off, 64);
    if ((t & 63) == 0) wso[WS_LOSS + (blk << 2) + (t >> 6)] = lsum;
}

// fused vq_reduce + vq_final: 64 blocks; last-block-done (cheap fences:
// each block has only ~4 KB of outstanding stores). Bodies verbatim from
// the R10 kernels -> bit-identical outputs.
__global__ __launch_bounds__(512) void vq_tail(float* __restrict__ ws,
                                               float* __restrict__ out)
{
    __shared__ int hist[512];
    __shared__ int s_last;
    const int b = blockIdx.x, t = threadIdx.x;
    const float* p = ws + WS_SHP + ((size_t)b << 14) + t;   // b*32*512
    float s = 0.f;
    #pragma unroll
    for (int j = 0; j < 32; ++j) s += p[j << 9];
    out[OFF_SH + (b << 9) + t] = s;
    hist[t] = 0;
    __syncthreads();
    const float* enc = out + OFF_ENC + ((size_t)b << 10);
    const int ca  = (int)enc[t];
    const int cbn = (int)enc[t + 512];
    atomicAdd(&hist[ca], 1);
    atomicAdd(&hist[cbn], 1);
    __syncthreads();
    out[OFF_IP + (b << 9) + t] = (float)hist[t];

    __threadfence();   // release this block's ip/sh writes
    if (t == 0) s_last = (atomicAdd(&((int*)ws)[WS_CNT], 1) == 63);
    __syncthreads();
    if (!s_last) return;
    __threadfence();   // acquire other blocks' ip writes

    // ---- vq_final body (verbatim) ----
    __shared__ float red[8], red2[8];
    const float* ip = out + OFF_IP;
    float c0 = 0.f, c1 = 0.f, c2 = 0.f, c3 = 0.f;
    #pragma unroll
    for (int bb = 0; bb < 64; bb += 4) {
        c0 += ip[((bb + 0) << 9) + t];
        c1 += ip[((bb + 1) << 9) + t];
        c2 += ip[((bb + 2) << 9) + t];
        c3 += ip[((bb + 3) << 9) + t];
    }
    const float c = (c0 + c1) + (c2 + c3);
    const float pav = c * (1.0f / 65536.f);
    float h = pav * logf(pav + 1e-10f);
    const float* wl = ws + WS_LOSS;
    float ls = 0.f;
    #pragma unroll
    for (int j = 0; j < 16; ++j) ls += wl[(j << 9) + t];
    #pragma unroll
    for (int off = 1; off < 64; off <<= 1) {
        h  += __shfl_xor(h, off, 64);
        ls += __shfl_xor(ls, off, 64);
    }
    if ((t & 63) == 0) { red[t >> 6] = h; red2[t >> 6] = ls; }
    __syncthreads();
    if (t == 0) {
        float H = 0.f, L = 0.f;
        #pragma unroll
        for (int w = 0; w < 8; ++w) { H += red[w]; L += red2[w]; }
        out[OFF_PERP] = expf(-H);
        out[OFF_LOSS] = L * (1.25f / 4194304.f);
    }
}

extern "C" void kernel_launch(void* const* d_in, const int* in_sizes, int n_in,
                              void* d_out, int out_size, void* d_ws, size_t ws_size,
                              hipStream_t stream)
{
    const float* x  = (const float*)d_in[0];
    const float* cb = (const float*)d_in[1];
    float* out = (float*)d_out;
    float* ws  = (float*)d_ws;
    (void)ws_size;   // requires >= 4.36 MB (1090049 floats)

    vq_prep <<<32,   256, 0, stream>>>(cb, ws);
    vq_main <<<2048, 256, 0, stream>>>(x, cb, ws, ws, out);
    vq_tail <<<64,   512, 0, stream>>>(ws, out);
}

// Round 12
// 175.124 us; speedup vs baseline: 1.5053x; 1.0985x over previous
//
#include <hip/hip_runtime.h>

// Problem constants (fixed by setup_inputs):
//   x: [B=64, D=64, H=32, W=32] fp32   -> N = B*H*W = 65536 rows of D=64
//   codebook: [K=512, D=64] fp32
// Output layout (all fp32, concatenated flat in return order):
//   [0 .. 4194304)        quant_out [B,D,H,W]
//   [4194304]             loss
//   [4194305]             perplexity
//   [4194306 .. +65536)   encoding_indice [B, H*W] (as float)
//   [4259842 .. +32768)   index_program [B,K]
//   [4292610 .. +32768)   softmax_histogram [B,K]

#define OFF_LOSS 4194304
#define OFF_PERP 4194305
#define OFF_ENC  4194306
#define OFF_IP   4259842
#define OFF_SH   4292610

// Workspace layout (floats). Requires ws_size >= 561729*4 B = 2.25 MB.
//   cbT  [4 segs][32 d][256 codes]  seg-major transposed codebook
//                                   (seg s = chunk*2 + d_half)
//   ce2  [512]               ||e_k||^2
//   sh partials [1024][512]  per-block softmax-histogram partial
//   loss partials [1024*4]   per-wave loss partial
//   counter [1] (int)        tail completion counter, zeroed by vq_prep
#define WS_CBT   0
#define WS_CE2   32768
#define WS_SHP   33280
#define WS_LOSS  557568
#define WS_CNT   561664

// R19 (GEMM read-count attack at R14's exact occupancy/liveness):
//  - Structure map (measured): R14 8x16/4-chunk @8 waves = 109us beats both
//    more-waves (R18: 12 waves, 126) and fewer (R17: 4 waves, 145). Lever:
//    per-wave LDS-unit time. A-fragments are re-read once per chunk.
//  - Fix: chunks 128 -> 256 codes (2 chunks): A-reads halve, 768 -> 512
//    ds_read_b128/thread (-33%). Chunks staged as TWO d-half segs (256
//    codes x 32 d = 32 KB) into the same single csT buffer -> LDS stays
//    50.5 KB, stage events stay 8 gloads, barrier count unchanged (7).
//  - Liveness unchanged vs R14 (one bq live: read quad0, 32 FMA, read
//    quad1, 32 FMA) -> no R17-style +4-reg occupancy cliff.
//  - k-mapping per thread unchanged: k = ((c>>2)<<7)+(tc<<2)+(c&3) (c>>2
//    now = (chunk,quad) 128-block). EPI/EXP/HIST/z-order/argmin/quant/
//    loss/tail VERBATIM R14 -> bit-identical outputs (per-(row,k) fmaf
//    chain still d 0..63 ascending).

typedef float f16v __attribute__((ext_vector_type(16)));

typedef __attribute__((address_space(1))) const void g_void;
typedef __attribute__((address_space(3))) void lds_void;
#define GLOAD_LDS(G, S) \
    __builtin_amdgcn_global_load_lds((g_void*)(G), (lds_void*)(S), 16, 0, 0)

__global__ __launch_bounds__(256) void vq_prep(const float* __restrict__ cb,
                                               float* __restrict__ ws)
{
    if (blockIdx.x == 0 && threadIdx.x == 0)
        ((int*)ws)[WS_CNT] = 0;   // every launch: graph-replay safe

    const int t  = blockIdx.x * 256 + threadIdx.x;   // 0..8191
    const int kg = t >> 4;                           // code 0..511
    const int j  = t & 15;                           // float4 index along D
    const float4 v = ((const float4*)cb)[(kg << 4) + j];
    float pr = v.x * v.x + v.y * v.y + v.z * v.z + v.w * v.w;
    #pragma unroll
    for (int off = 1; off < 16; off <<= 1) pr += __shfl_xor(pr, off, 16);
    if (j == 0) ws[WS_CE2 + kg] = pr;
    // seg-major: seg s = (chunk kc = kg>>8)*2 + (d-half h = j>>3)
    // within seg: [dl = 4j mod 32][kl = kg mod 256]
    const int s  = ((kg >> 8) << 1) + (j >> 3);
    const int dl = (j << 2) & 31;
    float* base = ws + WS_CBT + (s << 13) + (dl << 8) + (kg & 255);
    base[0]   = v.x;
    base[256] = v.y;
    base[512] = v.z;
    base[768] = v.w;
}

// ---- macro kit: all acc element indices are integer literals ----
#define FMA4(ACC, AV, K4) \
    ACC[(K4) + 0] = fmaf((AV), bq.x, ACC[(K4) + 0]); \
    ACC[(K4) + 1] = fmaf((AV), bq.y, ACC[(K4) + 1]); \
    ACC[(K4) + 2] = fmaf((AV), bq.z, ACC[(K4) + 2]); \
    ACC[(K4) + 3] = fmaf((AV), bq.w, ACC[(K4) + 3]);

// stage one 32 KB seg (256 codes x 32 d) of cbT into csT via global->LDS DMA
#define STAGE_SEG(S) do { \
    GLOAD_LDS(&cbT4[((S) << 11) + t],        &csT4[t]); \
    GLOAD_LDS(&cbT4[((S) << 11) + 256 + t],  &csT4[256 + t]); \
    GLOAD_LDS(&cbT4[((S) << 11) + 512 + t],  &csT4[512 + t]); \
    GLOAD_LDS(&cbT4[((S) << 11) + 768 + t],  &csT4[768 + t]); \
    GLOAD_LDS(&cbT4[((S) << 11) + 1024 + t], &csT4[1024 + t]); \
    GLOAD_LDS(&cbT4[((S) << 11) + 1280 + t], &csT4[1280 + t]); \
    GLOAD_LDS(&cbT4[((S) << 11) + 1536 + t], &csT4[1536 + t]); \
    GLOAD_LDS(&cbT4[((S) << 11) + 1792 + t], &csT4[1792 + t]); \
} while (0)

// 32-d FMA sweep over one seg (chunk KC, d-half H; both literals).
// Per d: 2 A-reads + 2 B-reads feed 64 FMA (8 rows x 8 cols). Only one bq
// live at a time (R14 liveness). Per (row,k): d ascending (H=0: 0..31,
// H=1: 32..63) -> R14's exact fmaf chain per accumulator element.
#define GEMM_SEG(KC, H) do { \
    _Pragma("unroll 2") \
    for (int db = 0; db < 8; ++db) { \
        _Pragma("unroll") \
        for (int j = 0; j < 4; ++j) { \
            const int dl = (db << 2) + j; \
            const int d  = ((H) << 5) + dl; \
            const float4 a0 = *(const float4*)&xs[(d << 6) + (tr << 3)]; \
            const float4 a1 = *(const float4*)&xs[(d << 6) + (tr << 3) + 4]; \
            const float* cb0 = &csT[(dl << 8) + (tc << 2)]; \
            { \
                const float4 bq = *(const float4*)cb0; \
                FMA4(acc0, a0.x, (KC) << 3) \
                FMA4(acc1, a0.y, (KC) << 3) \
                FMA4(acc2, a0.z, (KC) << 3) \
                FMA4(acc3, a0.w, (KC) << 3) \
                FMA4(acc4, a1.x, (KC) << 3) \
                FMA4(acc5, a1.y, (KC) << 3) \
                FMA4(acc6, a1.z, (KC) << 3) \
                FMA4(acc7, a1.w, (KC) << 3) \
            } \
            { \
                const float4 bq = *(const float4*)(cb0 + 128); \
                FMA4(acc0, a0.x, ((KC) << 3) + 4) \
                FMA4(acc1, a0.y, ((KC) << 3) + 4) \
                FMA4(acc2, a0.z, ((KC) << 3) + 4) \
                FMA4(acc3, a0.w, ((KC) << 3) + 4) \
                FMA4(acc4, a1.x, ((KC) << 3) + 4) \
                FMA4(acc5, a1.y, ((KC) << 3) + 4) \
                FMA4(acc6, a1.z, ((KC) << 3) + 4) \
                FMA4(acc7, a1.w, ((KC) << 3) + 4) \
            } \
        } \
    } \
} while (0)

#define EPI_C(C, ACC) { \
    const int k = (((C) >> 2) << 7) + (tc << 2) + ((C) & 3); \
    const float t1 = xxr + ce2[k]; \
    const float dist = t1 - 2.f * ACC[C]; \
    ACC[C] = dist; \
    if (dist < m) { m = dist; bk = k; } }

#define EXP_C(C, ACC) { \
    const float e = __expf(m - ACC[C]); \
    ACC[C] = e; z += e; }

#define ROW_EPI(I, ACC, INVZ) do { \
    const int row = (tr << 3) + (I); \
    const float xxr = sxx[row]; \
    float m = 1e30f; int bk = 0; \
    EPI_C(0, ACC)  EPI_C(1, ACC)  EPI_C(2, ACC)  EPI_C(3, ACC) \
    EPI_C(4, ACC)  EPI_C(5, ACC)  EPI_C(6, ACC)  EPI_C(7, ACC) \
    EPI_C(8, ACC)  EPI_C(9, ACC)  EPI_C(10, ACC) EPI_C(11, ACC) \
    EPI_C(12, ACC) EPI_C(13, ACC) EPI_C(14, ACC) EPI_C(15, ACC) \
    _Pragma("unroll") \
    for (int off = 1; off < 32; off <<= 1) { \
        const float mo = __shfl_xor(m, off, 32); \
        const int   ko = __shfl_xor(bk, off, 32); \
        if (mo < m || (mo == m && ko < bk)) { m = mo; bk = ko; } \
    } \
    float z = 0.f; \
    EXP_C(0, ACC)  EXP_C(1, ACC)  EXP_C(2, ACC)  EXP_C(3, ACC) \
    EXP_C(4, ACC)  EXP_C(5, ACC)  EXP_C(6, ACC)  EXP_C(7, ACC) \
    EXP_C(8, ACC)  EXP_C(9, ACC)  EXP_C(10, ACC) EXP_C(11, ACC) \
    EXP_C(12, ACC) EXP_C(13, ACC) EXP_C(14, ACC) EXP_C(15, ACC) \
    _Pragma("unroll") \
    for (int off = 1; off < 32; off <<= 1) z += __shfl_xor(z, off, 32); \
    INVZ = 1.f / z; \
    if (tc == 0) { \
        sidx[row] = bk; \
        enc[((size_t)b << 10) + row0 + row] = (float)bk; \
    } \
} while (0)

#define HIST_C(C) { \
    const int k = (((C) >> 2) << 7) + (tc << 2) + ((C) & 3); \
    float cs = 0.f; \
    cs += acc0[C] * invz0; cs += acc1[C] * invz1; \
    cs += acc2[C] * invz2; cs += acc3[C] * invz3; \
    cs += acc4[C] * invz4; cs += acc5[C] * invz5; \
    cs += acc6[C] * invz6; cs += acc7[C] * invz7; \
    atomicAdd(&shist[k], cs); }

__global__ __launch_bounds__(256, 1) void vq_main(
    const float* __restrict__ x, const float* __restrict__ cb,
    const float* __restrict__ wsc,   // cbT + ce2 (read-only region)
    float* __restrict__ wso,         // sh + loss partials (write-only region)
    float* __restrict__ out)
{
    __shared__ float  xs[64 * 64];     // xs[d*64 + r], transposed x tile
    __shared__ float  csT[32 * 256];   // [dl][k] for current seg (32 KB)
    __shared__ float  ce2[512];        // ||e_k||^2 (fp32)
    __shared__ float  sxx[64];         // ||x_r||^2 (fp32) per row
    __shared__ int    sidx[64];        // argmin code per row

    const int t    = threadIdx.x;
    const int blk  = blockIdx.x;        // 0..1023
    const int b    = blk >> 4;          // batch index
    const int row0 = (blk & 15) << 6;   // row offset within batch (H*W space)
    const int tr   = t >> 5;            // 0..7  (row group: rows tr*8..tr*8+7)
    const int tc   = t & 31;            // 0..31 (col group)

    const float4* cbT4 = (const float4*)(wsc + WS_CBT);
    float4* csT4 = (float4*)csT;

    // ---- stage x tile via global->LDS DMA (lane-linear: lds = base+lane*16) ----
    {
        const float4* xb4 = (const float4*)(x + ((size_t)b << 16) + row0);
        #pragma unroll
        for (int p = 0; p < 4; ++p) {
            const int fi = (p << 8) + t;      // 0..1023
            const int d  = fi >> 4;
            const int r4 = fi & 15;
            GLOAD_LDS(&xb4[(d << 8) + r4], &xs[(d << 6) + (r4 << 2)]);
        }
    }
    // ---- stage seg 0 (chunk 0, d 0..31) ----
    STAGE_SEG(0);
    // ---- stage ce2 from ws (plain load/store, drained by the barrier) ----
    if (t < 128) ((float4*)ce2)[t] = ((const float4*)(wsc + WS_CE2))[t];

    __syncthreads();   // drains vmcnt(0): xs + seg 0 + ce2 ready

    // ---- ||x_r||^2 fp32, sequential fmaf over d (bit-exact) ----
    if (t < 64) {
        float s = 0.f;
        for (int d = 0; d < 64; ++d) { const float v = xs[(d << 6) + t]; s = fmaf(v, v, s); }
        sxx[t] = s;
    }

    f16v acc0 = 0.f, acc1 = 0.f, acc2 = 0.f, acc3 = 0.f;
    f16v acc4 = 0.f, acc5 = 0.f, acc6 = 0.f, acc7 = 0.f;

    // ---- GEMM: 4 segs = 2 chunks x 2 d-halves (all indices literal) ----
    GEMM_SEG(0, 0);
    __syncthreads();   // all waves done reading seg 0
    STAGE_SEG(1);
    __syncthreads();   // vmcnt drained: seg 1 ready (sxx also visible)
    GEMM_SEG(0, 1);
    __syncthreads();
    STAGE_SEG(2);
    __syncthreads();
    GEMM_SEG(1, 0);
    __syncthreads();
    STAGE_SEG(3);
    __syncthreads();
    GEMM_SEG(1, 1);

    // ---- epilogue: ref-exact fp32 dist; per-row argmin + softmax(-dist) ----
    float* enc = out + OFF_ENC;
    float invz0, invz1, invz2, invz3, invz4, invz5, invz6, invz7;
    ROW_EPI(0, acc0, invz0);
    ROW_EPI(1, acc1, invz1);
    ROW_EPI(2, acc2, invz2);
    ROW_EPI(3, acc3, invz3);
    ROW_EPI(4, acc4, invz4);
    ROW_EPI(5, acc5, invz5);
    ROW_EPI(6, acc6, invz6);
    ROW_EPI(7, acc7, invz7);

    __syncthreads();   // all csT reads done; sidx visible

    // ---- softmax histogram: block-reduce in LDS (alias csT), partial to ws ----
    float* shist = csT;
    shist[t] = 0.f; shist[t + 256] = 0.f;
    __syncthreads();
    HIST_C(0)  HIST_C(1)  HIST_C(2)  HIST_C(3)
    HIST_C(4)  HIST_C(5)  HIST_C(6)  HIST_C(7)
    HIST_C(8)  HIST_C(9)  HIST_C(10) HIST_C(11)
    HIST_C(12) HIST_C(13) HIST_C(14) HIST_C(15)
    __syncthreads();
    {
        float* wsh = wso + WS_SHP + ((size_t)blk << 9);
        wsh[t]       = shist[t];
        wsh[t + 256] = shist[t + 256];
    }

    // ---- quantized output + loss partial (from sidx), vectorized ----
    const int r4 = (t & 15) << 2;          // row quad 0..60
    const int dq = t >> 4;                 // 0..15
    const int c0 = sidx[r4], c1 = sidx[r4 + 1], c2 = sidx[r4 + 2], c3 = sidx[r4 + 3];
    float lsum = 0.f;
    #pragma unroll
    for (int p = 0; p < 4; ++p) {
        const int d = (p << 4) + dq;
        float4 q;
        q.x = cb[(c0 << 6) + d];
        q.y = cb[(c1 << 6) + d];
        q.z = cb[(c2 << 6) + d];
        q.w = cb[(c3 << 6) + d];
        const float4 xv = *(const float4*)&xs[(d << 6) + r4];
        const float d0 = q.x - xv.x, d1 = q.y - xv.y, d2 = q.z - xv.z, d3 = q.w - xv.w;
        lsum = fmaf(d0, d0, lsum); lsum = fmaf(d1, d1, lsum);
        lsum = fmaf(d2, d2, lsum); lsum = fmaf(d3, d3, lsum);
        *(float4*)&out[(((size_t)(b << 6) + d) << 10) + row0 + r4] = q;
    }
    #pragma unroll
    for (int off = 1; off < 64; off <<= 1) lsum += __shfl_xor(lsum, off, 64);
    if ((t & 63) == 0) wso[WS_LOSS + (blk << 2) + (t >> 6)] = lsum;
}

// fused vq_reduce + vq_final: 64 blocks; last-block-done (cheap fences:
// each block has only ~4 KB of outstanding stores). Bodies verbatim from
// the R14 kernels -> bit-identical outputs.
__global__ __launch_bounds__(512) void vq_tail(float* __restrict__ ws,
                                               float* __restrict__ out)
{
    __shared__ int hist[512];
    __shared__ int s_last;
    const int b = blockIdx.x, t = threadIdx.x;
    const float* p = ws + WS_SHP + ((size_t)b << 13) + t;   // b*16*512
    float s = 0.f;
    #pragma unroll
    for (int j = 0; j < 16; ++j) s += p[j << 9];
    out[OFF_SH + (b << 9) + t] = s;
    hist[t] = 0;
    __syncthreads();
    const float* enc = out + OFF_ENC + ((size_t)b << 10);
    const int ca  = (int)enc[t];
    const int cbn = (int)enc[t + 512];
    atomicAdd(&hist[ca], 1);
    atomicAdd(&hist[cbn], 1);
    __syncthreads();
    out[OFF_IP + (b << 9) + t] = (float)hist[t];

    __threadfence();   // release this block's ip/sh writes
    if (t == 0) s_last = (atomicAdd(&((int*)ws)[WS_CNT], 1) == 63);
    __syncthreads();
    if (!s_last) return;
    __threadfence();   // acquire other blocks' ip writes

    // ---- vq_final body (verbatim) ----
    __shared__ float red[8], red2[8];
    const float* ip = out + OFF_IP;
    float c0 = 0.f, c1 = 0.f, c2 = 0.f, c3 = 0.f;
    #pragma unroll
    for (int bb = 0; bb < 64; bb += 4) {
        c0 += ip[((bb + 0) << 9) + t];
        c1 += ip[((bb + 1) << 9) + t];
        c2 += ip[((bb + 2) << 9) + t];
        c3 += ip[((bb + 3) << 9) + t];
    }
    const float c = (c0 + c1) + (c2 + c3);
    const float pav = c * (1.0f / 65536.f);
    float h = pav * logf(pav + 1e-10f);
    const float* wl = ws + WS_LOSS;
    float ls = 0.f;
    #pragma unroll
    for (int j = 0; j < 8; ++j) ls += wl[(j << 9) + t];
    #pragma unroll
    for (int off = 1; off < 64; off <<= 1) {
        h  += __shfl_xor(h, off, 64);
        ls += __shfl_xor(ls, off, 64);
    }
    if ((t & 63) == 0) { red[t >> 6] = h; red2[t >> 6] = ls; }
    __syncthreads();
    if (t == 0) {
        float H = 0.f, L = 0.f;
        #pragma unroll
        for (int w = 0; w < 8; ++w) { H += red[w]; L += red2[w]; }
        out[OFF_PERP] = expf(-H);
        out[OFF_LOSS] = L * (1.25f / 4194304.f);
    }
}

extern "C" void kernel_launch(void* const* d_in, const int* in_sizes, int n_in,
                              void* d_out, int out_size, void* d_ws, size_t ws_size,
                              hipStream_t stream)
{
    const float* x  = (const float*)d_in[0];
    const float* cb = (const float*)d_in[1];
    float* out = (float*)d_out;
    float* ws  = (float*)d_ws;
    (void)ws_size;   // requires >= 2.25 MB (561729 floats)

    vq_prep <<<32,   256, 0, stream>>>(cb, ws);
    vq_main <<<1024, 256, 0, stream>>>(x, cb, ws, ws, out);
    vq_tail <<<64,   512, 0, stream>>>(ws, out);
}

// Round 13
// 172.114 us; speedup vs baseline: 1.5316x; 1.0175x over previous
//
#include <hip/hip_runtime.h>

// Problem constants (fixed by setup_inputs):
//   x: [B=64, D=64, H=32, W=32] fp32   -> N = B*H*W = 65536 rows of D=64
//   codebook: [K=512, D=64] fp32
// Output layout (all fp32, concatenated flat in return order):
//   [0 .. 4194304)        quant_out [B,D,H,W]
//   [4194304]             loss
//   [4194305]             perplexity
//   [4194306 .. +65536)   encoding_indice [B, H*W] (as float)
//   [4259842 .. +32768)   index_program [B,K]
//   [4292610 .. +32768)   softmax_histogram [B,K]

#define OFF_LOSS 4194304
#define OFF_PERP 4194305
#define OFF_ENC  4194306
#define OFF_IP   4259842
#define OFF_SH   4292610

// Workspace layout (floats). Requires ws_size >= 561729*4 B = 2.25 MB.
//   cbT  [4 segs][16 d][512 codes]  d-seg-major transposed codebook
//                                   (seg s covers d in [16s, 16s+16))
//   ce2  [512]               ||e_k||^2
//   sh partials [1024][512]  per-block softmax-histogram partial
//   loss partials [1024*4]   per-wave loss partial
//   counter [1] (int)        tail completion counter, zeroed by vq_prep
#define WS_CBT   0
#define WS_CE2   32768
#define WS_SHP   33280
#define WS_LOSS  557568
#define WS_CNT   561664

// R20 (A-read elimination completed + epilogue ce2 vectorization):
//  - R19 measured: reads 768->512 gave 109->103us; at 2 waves/SIMD the
//    kernel is latency-bound (VALUBusy 43%, LDS pipe ~40% busy), so reads
//    matter via issue+latency exposure. R19 still re-reads A once/chunk.
//  - (a) Segs re-cut along d only: seg = ALL 512 codes x 16 d (same 32 KB
//    buffer, 8 gloads, 7 barriers). Per d: 2 A + 4 B reads feed all 16
//    cols -> 384 reads/thread (A 256->128). acc indices = k-quad literals;
//    per-(row,k) fmaf chain still d=0..63 ascending -> bit-exact. One bq
//    live at a time -> liveness = R19 (no R17 reg cliff).
//  - (b) ROW_EPI ce2: 16 scalar LDS reads/row -> 4 float4 reads/row
//    (contiguous at (q<<7)+(tc<<2); conflict-free). Same values, same add
//    order -> bit-exact. 128 -> 32 epilogue LDS reads/thread.

typedef float f16v __attribute__((ext_vector_type(16)));

typedef __attribute__((address_space(1))) const void g_void;
typedef __attribute__((address_space(3))) void lds_void;
#define GLOAD_LDS(G, S) \
    __builtin_amdgcn_global_load_lds((g_void*)(G), (lds_void*)(S), 16, 0, 0)

__global__ __launch_bounds__(256) void vq_prep(const float* __restrict__ cb,
                                               float* __restrict__ ws)
{
    if (blockIdx.x == 0 && threadIdx.x == 0)
        ((int*)ws)[WS_CNT] = 0;   // every launch: graph-replay safe

    const int t  = blockIdx.x * 256 + threadIdx.x;   // 0..8191
    const int kg = t >> 4;                           // code 0..511
    const int j  = t & 15;                           // float4 index along D
    const float4 v = ((const float4*)cb)[(kg << 4) + j];
    float pr = v.x * v.x + v.y * v.y + v.z * v.z + v.w * v.w;
    #pragma unroll
    for (int off = 1; off < 16; off <<= 1) pr += __shfl_xor(pr, off, 16);
    if (j == 0) ws[WS_CE2 + kg] = pr;
    // d-seg-major: seg s = d/16 = j>>2; within seg [dl = 4j mod 16][k]
    const int s   = j >> 2;
    const int dl4 = (j & 3) << 2;
    float* base = ws + WS_CBT + (s << 13) + (dl4 << 9) + kg;
    base[0]    = v.x;
    base[512]  = v.y;
    base[1024] = v.z;
    base[1536] = v.w;
}

// ---- macro kit: all acc element indices are integer literals ----
#define FMA4(ACC, AV, K4) \
    ACC[(K4) + 0] = fmaf((AV), bq.x, ACC[(K4) + 0]); \
    ACC[(K4) + 1] = fmaf((AV), bq.y, ACC[(K4) + 1]); \
    ACC[(K4) + 2] = fmaf((AV), bq.z, ACC[(K4) + 2]); \
    ACC[(K4) + 3] = fmaf((AV), bq.w, ACC[(K4) + 3]);

// stage one 32 KB seg (512 codes x 16 d) of cbT into csT via global->LDS DMA
#define STAGE_SEG(S) do { \
    GLOAD_LDS(&cbT4[((S) << 11) + t],        &csT4[t]); \
    GLOAD_LDS(&cbT4[((S) << 11) + 256 + t],  &csT4[256 + t]); \
    GLOAD_LDS(&cbT4[((S) << 11) + 512 + t],  &csT4[512 + t]); \
    GLOAD_LDS(&cbT4[((S) << 11) + 768 + t],  &csT4[768 + t]); \
    GLOAD_LDS(&cbT4[((S) << 11) + 1024 + t], &csT4[1024 + t]); \
    GLOAD_LDS(&cbT4[((S) << 11) + 1280 + t], &csT4[1280 + t]); \
    GLOAD_LDS(&cbT4[((S) << 11) + 1536 + t], &csT4[1536 + t]); \
    GLOAD_LDS(&cbT4[((S) << 11) + 1792 + t], &csT4[1792 + t]); \
} while (0)

// one k-quad's FMA block at LDS depth-base CB0 (quad Q literal)
#define FMA_QUAD(Q, OFFS) do { \
    const float4 bq = *(const float4*)(cb0 + (OFFS)); \
    FMA4(acc0, a0.x, (Q) << 2) \
    FMA4(acc1, a0.y, (Q) << 2) \
    FMA4(acc2, a0.z, (Q) << 2) \
    FMA4(acc3, a0.w, (Q) << 2) \
    FMA4(acc4, a1.x, (Q) << 2) \
    FMA4(acc5, a1.y, (Q) << 2) \
    FMA4(acc6, a1.z, (Q) << 2) \
    FMA4(acc7, a1.w, (Q) << 2) \
} while (0)

// 16-d FMA sweep over one seg (full K=512 per d). Per (row,k): d ascending
// within seg, segs ascending -> d = 0..63 ascending, R19's exact chain.
#define GEMM_SEG(S) do { \
    _Pragma("unroll 4") \
    for (int dl = 0; dl < 16; ++dl) { \
        const int d = ((S) << 4) + dl; \
        const float4 a0 = *(const float4*)&xs[(d << 6) + (tr << 3)]; \
        const float4 a1 = *(const float4*)&xs[(d << 6) + (tr << 3) + 4]; \
        const float* cb0 = &csT[(dl << 9) + (tc << 2)]; \
        FMA_QUAD(0, 0); \
        FMA_QUAD(1, 128); \
        FMA_QUAD(2, 256); \
        FMA_QUAD(3, 384); \
    } \
} while (0)

#define EPI_C(C, ACC, CE) { \
    const int k = (((C) >> 2) << 7) + (tc << 2) + ((C) & 3); \
    const float t1 = xxr + (CE); \
    const float dist = t1 - 2.f * ACC[C]; \
    ACC[C] = dist; \
    if (dist < m) { m = dist; bk = k; } }

#define EPI_Q(Q, ACC) { \
    const float4 cq = *(const float4*)&ce2[((Q) << 7) + (tc << 2)]; \
    EPI_C(((Q) << 2) + 0, ACC, cq.x) \
    EPI_C(((Q) << 2) + 1, ACC, cq.y) \
    EPI_C(((Q) << 2) + 2, ACC, cq.z) \
    EPI_C(((Q) << 2) + 3, ACC, cq.w) }

#define EXP_C(C, ACC) { \
    const float e = __expf(m - ACC[C]); \
    ACC[C] = e; z += e; }

#define ROW_EPI(I, ACC, INVZ) do { \
    const int row = (tr << 3) + (I); \
    const float xxr = sxx[row]; \
    float m = 1e30f; int bk = 0; \
    EPI_Q(0, ACC)  EPI_Q(1, ACC)  EPI_Q(2, ACC)  EPI_Q(3, ACC) \
    _Pragma("unroll") \
    for (int off = 1; off < 32; off <<= 1) { \
        const float mo = __shfl_xor(m, off, 32); \
        const int   ko = __shfl_xor(bk, off, 32); \
        if (mo < m || (mo == m && ko < bk)) { m = mo; bk = ko; } \
    } \
    float z = 0.f; \
    EXP_C(0, ACC)  EXP_C(1, ACC)  EXP_C(2, ACC)  EXP_C(3, ACC) \
    EXP_C(4, ACC)  EXP_C(5, ACC)  EXP_C(6, ACC)  EXP_C(7, ACC) \
    EXP_C(8, ACC)  EXP_C(9, ACC)  EXP_C(10, ACC) EXP_C(11, ACC) \
    EXP_C(12, ACC) EXP_C(13, ACC) EXP_C(14, ACC) EXP_C(15, ACC) \
    _Pragma("unroll") \
    for (int off = 1; off < 32; off <<= 1) z += __shfl_xor(z, off, 32); \
    INVZ = 1.f / z; \
    if (tc == 0) { \
        sidx[row] = bk; \
        enc[((size_t)b << 10) + row0 + row] = (float)bk; \
    } \
} while (0)

#define HIST_C(C) { \
    const int k = (((C) >> 2) << 7) + (tc << 2) + ((C) & 3); \
    float cs = 0.f; \
    cs += acc0[C] * invz0; cs += acc1[C] * invz1; \
    cs += acc2[C] * invz2; cs += acc3[C] * invz3; \
    cs += acc4[C] * invz4; cs += acc5[C] * invz5; \
    cs += acc6[C] * invz6; cs += acc7[C] * invz7; \
    atomicAdd(&shist[k], cs); }

__global__ __launch_bounds__(256, 1) void vq_main(
    const float* __restrict__ x, const float* __restrict__ cb,
    const float* __restrict__ wsc,   // cbT + ce2 (read-only region)
    float* __restrict__ wso,         // sh + loss partials (write-only region)
    float* __restrict__ out)
{
    __shared__ float  xs[64 * 64];     // xs[d*64 + r], transposed x tile
    __shared__ float  csT[16 * 512];   // [dl][k] for current seg (32 KB)
    __shared__ float  ce2[512];        // ||e_k||^2 (fp32)
    __shared__ float  sxx[64];         // ||x_r||^2 (fp32) per row
    __shared__ int    sidx[64];        // argmin code per row

    const int t    = threadIdx.x;
    const int blk  = blockIdx.x;        // 0..1023
    const int b    = blk >> 4;          // batch index
    const int row0 = (blk & 15) << 6;   // row offset within batch (H*W space)
    const int tr   = t >> 5;            // 0..7  (row group: rows tr*8..tr*8+7)
    const int tc   = t & 31;            // 0..31 (col group)

    const float4* cbT4 = (const float4*)(wsc + WS_CBT);
    float4* csT4 = (float4*)csT;

    // ---- stage x tile via global->LDS DMA (lane-linear: lds = base+lane*16) ----
    {
        const float4* xb4 = (const float4*)(x + ((size_t)b << 16) + row0);
        #pragma unroll
        for (int p = 0; p < 4; ++p) {
            const int fi = (p << 8) + t;      // 0..1023
            const int d  = fi >> 4;
            const int r4 = fi & 15;
            GLOAD_LDS(&xb4[(d << 8) + r4], &xs[(d << 6) + (r4 << 2)]);
        }
    }
    // ---- stage seg 0 (d 0..15, all 512 codes) ----
    STAGE_SEG(0);
    // ---- stage ce2 from ws (plain load/store, drained by the barrier) ----
    if (t < 128) ((float4*)ce2)[t] = ((const float4*)(wsc + WS_CE2))[t];

    __syncthreads();   // drains vmcnt(0): xs + seg 0 + ce2 ready

    // ---- ||x_r||^2 fp32, sequential fmaf over d (bit-exact) ----
    if (t < 64) {
        float s = 0.f;
        for (int d = 0; d < 64; ++d) { const float v = xs[(d << 6) + t]; s = fmaf(v, v, s); }
        sxx[t] = s;
    }

    f16v acc0 = 0.f, acc1 = 0.f, acc2 = 0.f, acc3 = 0.f;
    f16v acc4 = 0.f, acc5 = 0.f, acc6 = 0.f, acc7 = 0.f;

    // ---- GEMM: 4 d-segs, full K per seg (all acc indices literal) ----
    GEMM_SEG(0);
    __syncthreads();   // all waves done reading seg 0
    STAGE_SEG(1);
    __syncthreads();   // vmcnt drained: seg 1 ready (sxx also visible)
    GEMM_SEG(1);
    __syncthreads();
    STAGE_SEG(2);
    __syncthreads();
    GEMM_SEG(2);
    __syncthreads();
    STAGE_SEG(3);
    __syncthreads();
    GEMM_SEG(3);

    // ---- epilogue: ref-exact fp32 dist; per-row argmin + softmax(-dist) ----
    float* enc = out + OFF_ENC;
    float invz0, invz1, invz2, invz3, invz4, invz5, invz6, invz7;
    ROW_EPI(0, acc0, invz0);
    ROW_EPI(1, acc1, invz1);
    ROW_EPI(2, acc2, invz2);
    ROW_EPI(3, acc3, invz3);
    ROW_EPI(4, acc4, invz4);
    ROW_EPI(5, acc5, invz5);
    ROW_EPI(6, acc6, invz6);
    ROW_EPI(7, acc7, invz7);

    __syncthreads();   // all csT reads done; sidx visible

    // ---- softmax histogram: block-reduce in LDS (alias csT), partial to ws ----
    float* shist = csT;
    shist[t] = 0.f; shist[t + 256] = 0.f;
    __syncthreads();
    HIST_C(0)  HIST_C(1)  HIST_C(2)  HIST_C(3)
    HIST_C(4)  HIST_C(5)  HIST_C(6)  HIST_C(7)
    HIST_C(8)  HIST_C(9)  HIST_C(10) HIST_C(11)
    HIST_C(12) HIST_C(13) HIST_C(14) HIST_C(15)
    __syncthreads();
    {
        float* wsh = wso + WS_SHP + ((size_t)blk << 9);
        wsh[t]       = shist[t];
        wsh[t + 256] = shist[t + 256];
    }

    // ---- quantized output + loss partial (from sidx), vectorized ----
    const int r4 = (t & 15) << 2;          // row quad 0..60
    const int dq = t >> 4;                 // 0..15
    const int c0 = sidx[r4], c1 = sidx[r4 + 1], c2 = sidx[r4 + 2], c3 = sidx[r4 + 3];
    float lsum = 0.f;
    #pragma unroll
    for (int p = 0; p < 4; ++p) {
        const int d = (p << 4) + dq;
        float4 q;
        q.x = cb[(c0 << 6) + d];
        q.y = cb[(c1 << 6) + d];
        q.z = cb[(c2 << 6) + d];
        q.w = cb[(c3 << 6) + d];
        const float4 xv = *(const float4*)&xs[(d << 6) + r4];
        const float d0 = q.x - xv.x, d1 = q.y - xv.y, d2 = q.z - xv.z, d3 = q.w - xv.w;
        lsum = fmaf(d0, d0, lsum); lsum = fmaf(d1, d1, lsum);
        lsum = fmaf(d2, d2, lsum); lsum = fmaf(d3, d3, lsum);
        *(float4*)&out[(((size_t)(b << 6) + d) << 10) + row0 + r4] = q;
    }
    #pragma unroll
    for (int off = 1; off < 64; off <<= 1) lsum += __shfl_xor(lsum, off, 64);
    if ((t & 63) == 0) wso[WS_LOSS + (blk << 2) + (t >> 6)] = lsum;
}

// fused vq_reduce + vq_final: 64 blocks; last-block-done (cheap fences:
// each block has only ~4 KB of outstanding stores). Bodies verbatim from
// the R14 kernels -> bit-identical outputs.
__global__ __launch_bounds__(512) void vq_tail(float* __restrict__ ws,
                                               float* __restrict__ out)
{
    __shared__ int hist[512];
    __shared__ int s_last;
    const int b = blockIdx.x, t = threadIdx.x;
    const float* p = ws + WS_SHP + ((size_t)b << 13) + t;   // b*16*512
    float s = 0.f;
    #pragma unroll
    for (int j = 0; j < 16; ++j) s += p[j << 9];
    out[OFF_SH + (b << 9) + t] = s;
    hist[t] = 0;
    __syncthreads();
    const float* enc = out + OFF_ENC + ((size_t)b << 10);
    const int ca  = (int)enc[t];
    const int cbn = (int)enc[t + 512];
    atomicAdd(&hist[ca], 1);
    atomicAdd(&hist[cbn], 1);
    __syncthreads();
    out[OFF_IP + (b << 9) + t] = (float)hist[t];

    __threadfence();   // release this block's ip/sh writes
    if (t == 0) s_last = (atomicAdd(&((int*)ws)[WS_CNT], 1) == 63);
    __syncthreads();
    if (!s_last) return;
    __threadfence();   // acquire other blocks' ip writes

    // ---- vq_final body (verbatim) ----
    __shared__ float red[8], red2[8];
    const float* ip = out + OFF_IP;
    float c0 = 0.f, c1 = 0.f, c2 = 0.f, c3 = 0.f;
    #pragma unroll
    for (int bb = 0; bb < 64; bb += 4) {
        c0 += ip[((bb + 0) << 9) + t];
        c1 += ip[((bb + 1) << 9) + t];
        c2 += ip[((bb + 2) << 9) + t];
        c3 += ip[((bb + 3) << 9) + t];
    }
    const float c = (c0 + c1) + (c2 + c3);
    const float pav = c * (1.0f / 65536.f);
    float h = pav * logf(pav + 1e-10f);
    const float* wl = ws + WS_LOSS;
    float ls = 0.f;
    #pragma unroll
    for (int j = 0; j < 8; ++j) ls += wl[(j << 9) + t];
    #pragma unroll
    for (int off = 1; off < 64; off <<= 1) {
        h  += __shfl_xor(h, off, 64);
        ls += __shfl_xor(ls, off, 64);
    }
    if ((t & 63) == 0) { red[t >> 6] = h; red2[t >> 6] = ls; }
    __syncthreads();
    if (t == 0) {
        float H = 0.f, L = 0.f;
        #pragma unroll
        for (int w = 0; w < 8; ++w) { H += red[w]; L += red2[w]; }
        out[OFF_PERP] = expf(-H);
        out[OFF_LOSS] = L * (1.25f / 4194304.f);
    }
}

extern "C" void kernel_launch(void* const* d_in, const int* in_sizes, int n_in,
                              void* d_out, int out_size, void* d_ws, size_t ws_size,
                              hipStream_t stream)
{
    const float* x  = (const float*)d_in[0];
    const float* cb = (const float*)d_in[1];
    float* out = (float*)d_out;
    float* ws  = (float*)d_ws;
    (void)ws_size;   // requires >= 2.25 MB (561729 floats)

    vq_prep <<<32,   256, 0, stream>>>(cb, ws);
    vq_main <<<1024, 256, 0, stream>>>(x, cb, ws, ws, out);
    vq_tail <<<64,   512, 0, stream>>>(ws, out);
}